// Round 10
// baseline (504.477 us; speedup 1.0000x reference)
//
#include <hip/hip_runtime.h>
#include <stdint.h>

#define BATCH   16
#define NANCH   25200
#define NCLS    80
#define REC     85
#define MAXDET  300
#define TMAX    50
#define NBUCKET 2048
#define FIN     512
#define REPEAT  8   // MEASUREMENT ROUND: inflate kA2/kBCD 8x to read their true dur_us

// output offsets (floats)
#define OFF_PB 0
#define OFF_PS 19200
#define OFF_PL 24000
#define OFF_PK 28800
#define OFF_TB 33600
#define OFF_TS 36800
#define OFF_TL 37600
#define OFF_TV 38400

__device__ __forceinline__ float opaque_f(float x) { asm volatile("" : "+v"(x)); return x; }

// ---- Kernel A1: extract obj field -> dense objarr (unchanged, clean ref) ----
__global__ __launch_bounds__(256) void kA1(const float* __restrict__ logits,
                                           float* __restrict__ objarr) {
    const int g = blockIdx.x * 256 + threadIdx.x;     // 1575*256 == 403200 exact
    objarr[g] = logits[(size_t)g * REC + 4];
}

// ---- Kernel A2: sparse score+label, x8 idempotent repeats ----
__global__ __launch_bounds__(256) void kA2(const float* __restrict__ logits,
                                           const float* __restrict__ objarr,
                                           unsigned* __restrict__ confout,
                                           unsigned* __restrict__ labout) {
    const int wid  = (blockIdx.x * 256 + threadIdx.x) >> 6;   // global wave id
    const int lane = threadIdx.x & 63;
    const int t    = lane >> 2;                               // anchor slot 0..15
    const int j    = lane & 3;                                // quarter 0..3
    const int a    = wid * 16 + t;                            // 25200 waves exact
    for (int rep = 0; rep < REPEAT; ++rep) {
        const float obj = objarr[a];                          // dense, broadcast x4
        unsigned cf = 0u;
        if (obj > 0.8f) {                                     // necessary for conf>0.8
            const float* cls = logits + (size_t)a * REC + 5 + j * 20;
            float v[20];
#pragma unroll
            for (int i = 0; i < 5; ++i) {
                float4 q = *(const float4*)(cls + 4 * i);
                v[4*i+0] = q.x; v[4*i+1] = q.y; v[4*i+2] = q.z; v[4*i+3] = q.w;
            }
            float m = v[0];
#pragma unroll
            for (int i = 1; i < 20; ++i) m = fmaxf(m, v[i]);
            m = fmaxf(m, __shfl_xor(m, 1));                   // within 4-group
            m = fmaxf(m, __shfl_xor(m, 2));                   // all 4 lanes agree
            int lc = 255;                                     // first-match class
#pragma unroll
            for (int i = 0; i < 20; ++i) lc = min(lc, (v[i] == m) ? (j * 20 + i) : 255);
            lc = min(lc, __shfl_xor(lc, 1));
            lc = min(lc, __shfl_xor(lc, 2));                  // global first-max idx
            const float conf = obj * m;                       // exact: single multiply
            cf = (conf > 0.8f) ? __float_as_uint(conf) : 0u;
            if (j == 0) labout[a] = (unsigned)lc;             // idempotent
        }
        if (j == 0) confout[a] = cf;                          // idempotent
        asm volatile("" ::: "memory");                        // no hoist/CSE across reps
    }
}

// ------- Kernel BCD: x8 idempotent repeats of the full R9 body -------
__global__ __launch_bounds__(1024) void kBCD(const float* __restrict__ logits,
                                             const unsigned* __restrict__ confbits,
                                             const unsigned* __restrict__ labels,
                                             const float* __restrict__ targets,
                                             const int* __restrict__ tlen,
                                             float* __restrict__ out) {
    __shared__ unsigned hist[NBUCKET];
    __shared__ unsigned long long fin[FIN];
    __shared__ unsigned long long srt[MAXDET];
    __shared__ float bx1[MAXDET], by1[MAXDET], bx2[MAXDET], by2[MAXDET];
    __shared__ unsigned supp[MAXDET * 10];   // 300 rows x 320 bits
    __shared__ unsigned keepw[10];
    __shared__ int sTb, sCnt;
    const int b = blockIdx.x;
    const int tid = threadIdx.x;
    const int lane = tid & 63;

    for (int rep = 0; rep < REPEAT; ++rep) {

    // ---- targets (kD), folded into spare threads ----
    if (tid >= 512 && tid < 512 + TMAX) {
        int t = tid - 512;
        bool is64 = (tlen[1] == 0) && (tlen[3] == 0) && (tlen[5] == 0);
        int len = is64 ? tlen[2 * b] : tlen[b];
        const float* r = targets + ((size_t)b * TMAX + t) * 6;
        float cx = r[0], cy = r[1], w = r[2], h = r[3], sc = r[4], lb = r[5];
        float hw = opaque_f(w * 0.5f);
        float hh = opaque_f(h * 0.5f);
        size_t o = (size_t)b * TMAX + t;
        out[OFF_TB + o * 4 + 0] = cx - hw;
        out[OFF_TB + o * 4 + 1] = cy - hh;
        out[OFF_TB + o * 4 + 2] = cx + hw;
        out[OFF_TB + o * 4 + 3] = cy + hh;
        out[OFF_TS + o] = sc;
        out[OFF_TL + o] = (float)(int)lb;
        out[OFF_TV + o] = (t < len) ? 1.0f : 0.0f;
    }

    // ---- init ----
    for (int i = tid; i < NBUCKET; i += 1024) hist[i] = 0u;
    for (int i = tid; i < MAXDET * 10; i += 1024) supp[i] = 0u;
    if (tid < MAXDET) srt[tid] = 0ull;
    if (tid == 0) sCnt = 0;
    __syncthreads();

    // ---- histogram over this batch's conf bits (uint4: 6300 groups) ----
    const unsigned* cb = confbits + (size_t)b * NANCH;
    const uint4* cb4 = (const uint4*)cb;
#pragma unroll 1
    for (int i = tid; i < NANCH / 4; i += 1024) {
        uint4 u = cb4[i];
        unsigned w0 = u.x, w1 = u.y, w2 = u.z, w3 = u.w;
        if (w0) { unsigned bk = (w0 - 0x3F4CCCCDu) >> 11; if (bk > NBUCKET-1u) bk = NBUCKET-1u; atomicAdd(&hist[bk], 1u); }
        if (w1) { unsigned bk = (w1 - 0x3F4CCCCDu) >> 11; if (bk > NBUCKET-1u) bk = NBUCKET-1u; atomicAdd(&hist[bk], 1u); }
        if (w2) { unsigned bk = (w2 - 0x3F4CCCCDu) >> 11; if (bk > NBUCKET-1u) bk = NBUCKET-1u; atomicAdd(&hist[bk], 1u); }
        if (w3) { unsigned bk = (w3 - 0x3F4CCCCDu) >> 11; if (bk > NBUCKET-1u) bk = NBUCKET-1u; atomicAdd(&hist[bk], 1u); }
    }
    __syncthreads();

    // ---- threshold bucket tb, wave 0 ----
    if (tid < 64) {
        const int l = tid;
        unsigned sup = 0u;
        for (int j = 0; j < 32; ++j) sup += hist[l * 32 + j];
        unsigned ss = sup;
        for (int off = 1; off < 64; off <<= 1) {
            unsigned v = __shfl_down(ss, off);
            ss += (l + off < 64) ? v : 0u;
        }
        bool ge = ss >= MAXDET;
        unsigned long long mask = __ballot(ge);
        int sstar = (mask == 0ull) ? 0 : (63 - __clzll(mask));
        unsigned tail = (sstar < 63) ? __shfl(ss, sstar + 1) : 0u;
        unsigned h = (l < 32) ? hist[sstar * 32 + l] : 0u;
        unsigned s2 = h;
        for (int off = 1; off < 32; off <<= 1) {
            unsigned v = __shfl_down(s2, off);
            s2 += (l + off < 32) ? v : 0u;
        }
        bool ge2 = (l < 32) && (s2 + tail >= MAXDET);
        unsigned long long m2 = __ballot(ge2);
        int lstar = (m2 == 0ull) ? 0 : (63 - __clzll(m2));
        if (l == 0) sTb = sstar * 32 + lstar;
    }
    __syncthreads();

    // ---- compact >= threshold into fin[]; wave-aggregated atomics ----
    const int tb = sTb;
#pragma unroll 1
    for (int i = tid; i < NANCH / 4; i += 1024) {
        uint4 u = cb4[i];
        unsigned wsv[4] = {u.x, u.y, u.z, u.w};
#pragma unroll
        for (int c = 0; c < 4; ++c) {
            unsigned bits = wsv[c];
            unsigned bk = (bits - 0x3F4CCCCDu) >> 11;
            if (bk > NBUCKET - 1u) bk = NBUCKET - 1u;
            bool pass = bits && ((int)bk >= tb);
            unsigned long long mk = __ballot(pass);
            if (mk) {
                int base = 0;
                if (lane == 0) base = atomicAdd(&sCnt, __popcll(mk));
                base = __shfl(base, 0);
                if (pass) {
                    int p = base + __popcll(mk & ((1ull << lane) - 1ull));
                    if (p < FIN)
                        fin[p] = ((unsigned long long)bits << 32) |
                                 (unsigned)(0xFFFFFFFFu - (unsigned)(i * 4 + c));
                }
            }
        }
    }
    __syncthreads();
    const int fc = (sCnt < FIN) ? sCnt : FIN;

    // ---- rank-scatter sort ----
    if (tid < fc) {
        unsigned long long k = fin[tid];
        int r = 0;
        for (int j = 0; j < fc; ++j) r += (fin[j] > k) ? 1 : 0;
        if (r < MAXDET) srt[r] = k;
    }
    __syncthreads();

    // ---- gather top-300: box float4 + precomputed label ----
    if (tid < MAXDET) {
        unsigned long long key = srt[tid];
        float score = __uint_as_float((unsigned)(key >> 32));
        unsigned n = 0xFFFFFFFFu - (unsigned)(key & 0xFFFFFFFFull);
        if (n >= NANCH) n = 0;
        const size_t ga = (size_t)b * NANCH + n;
        float4 bq = *(const float4*)(logits + ga * REC);
        unsigned lab = labels[ga];
        float hw = opaque_f(bq.z * 0.5f);
        float hh = opaque_f(bq.w * 0.5f);
        float x1 = bq.x - hw, y1 = bq.y - hh, x2 = bq.x + hw, y2 = bq.y + hh;
        bx1[tid] = x1; by1[tid] = y1; bx2[tid] = x2; by2[tid] = y2;
        size_t o = (size_t)(b * MAXDET + tid);
        out[OFF_PB + o * 4 + 0] = x1;
        out[OFF_PB + o * 4 + 1] = y1;
        out[OFF_PB + o * 4 + 2] = x2;
        out[OFF_PB + o * 4 + 3] = y2;
        out[OFF_PS + o] = score;
        out[OFF_PL + o] = (float)lab;
    }
    __syncthreads();

    // ---- suppression matrix ----
    for (int p = tid; p < MAXDET * MAXDET; p += 1024) {
        int i = p / MAXDET;
        int j = p - i * MAXDET;
        if (j > i) {
            float ai = (bx2[i] - bx1[i]) * (by2[i] - by1[i]);
            float aj = (bx2[j] - bx1[j]) * (by2[j] - by1[j]);
            float ltx = fmaxf(bx1[i], bx1[j]);
            float lty = fmaxf(by1[i], by1[j]);
            float rbx = fminf(bx2[i], bx2[j]);
            float rby = fminf(by2[i], by2[j]);
            float wx = fmaxf(rbx - ltx, 0.0f);
            float wy = fmaxf(rby - lty, 0.0f);
            float inter = wx * wy;
            float iou = inter / (ai + aj - inter + 1e-9f);
            if (iou > 0.4f) atomicOr(&supp[i * 10 + (j >> 5)], 1u << (j & 31));
        }
    }
    __syncthreads();

    // ---- greedy scan ----
    if (tid < 64) {
        int q = tid;
        unsigned kw = (q < 10) ? ((q == 9) ? 0xFFFu : 0xFFFFFFFFu) : 0u;
        unsigned nextrow = (q < 10) ? supp[q] : 0u;
        for (int i = 0; i < MAXDET; ++i) {
            unsigned rowq = nextrow;
            if (q < 10 && i + 1 < MAXDET) nextrow = supp[(i + 1) * 10 + q];
            bool mybit = (q == (i >> 5)) && ((kw >> (i & 31)) & 1u);
            if (__ballot(mybit)) kw &= ~rowq;
        }
        if (q < 10) keepw[q] = kw;
    }
    __syncthreads();
    if (tid < MAXDET)
        out[OFF_PK + (size_t)b * MAXDET + tid] =
            ((keepw[tid >> 5] >> (tid & 31)) & 1u) ? 1.0f : 0.0f;

    __syncthreads();                       // buffers reused next rep
    asm volatile("" ::: "memory");         // no hoist/CSE across reps
    }  // rep
}

extern "C" void kernel_launch(void* const* d_in, const int* in_sizes, int n_in,
                              void* d_out, int out_size, void* d_ws, size_t ws_size,
                              hipStream_t stream) {
    const float* logits  = (const float*)d_in[0];
    const float* targets = (const float*)d_in[1];
    const int*   tlen    = (const int*)d_in[2];
    float* out = (float*)d_out;
    char* ws = (char*)d_ws;
    unsigned* confbits = (unsigned*)ws;                                 // 403200 u32
    unsigned* labels   = (unsigned*)(ws + (size_t)BATCH * NANCH * 4);   // 403200 u32
    float*    objarr   = (float*)   (ws + (size_t)BATCH * NANCH * 8);   // 403200 f32

    hipLaunchKernelGGL(kA1, dim3(1575), dim3(256), 0, stream, logits, objarr);
    hipLaunchKernelGGL(kA2, dim3(6300), dim3(256), 0, stream,
                       logits, objarr, confbits, labels);
    hipLaunchKernelGGL(kBCD, dim3(BATCH), dim3(1024), 0, stream,
                       logits, confbits, labels, targets, tlen, out);
}

// Round 11
// 76.730 us; speedup vs baseline: 6.5747x; 6.5747x over previous
//
#include <hip/hip_runtime.h>
#include <stdint.h>

#define BATCH   16
#define NANCH   25200
#define NCLS    80
#define REC     85
#define MAXDET  300
#define TMAX    50
#define NBUCKET 2048
#define FIN     512
#define SUPW    3008   // padded words per batch for supp matrix (300*10 used)

// output offsets (floats)
#define OFF_PB 0
#define OFF_PS 19200
#define OFF_PL 24000
#define OFF_PK 28800
#define OFF_TB 33600
#define OFF_TS 36800
#define OFF_TL 37600
#define OFF_TV 38400

__device__ __forceinline__ float opaque_f(float x) { asm volatile("" : "+v"(x)); return x; }

// ---- Kernel A1: extract obj field -> dense objarr ----
__global__ __launch_bounds__(256) void kA1(const float* __restrict__ logits,
                                           float* __restrict__ objarr) {
    const int g = blockIdx.x * 256 + threadIdx.x;     // 1575*256 == 403200 exact
    objarr[g] = logits[(size_t)g * REC + 4];
}

// ---- Kernel A2: sparse score+label (conf>0.8 requires obj>0.8) ----
__global__ __launch_bounds__(256) void kA2(const float* __restrict__ logits,
                                           const float* __restrict__ objarr,
                                           unsigned* __restrict__ confout,
                                           unsigned* __restrict__ labout) {
    const int wid  = (blockIdx.x * 256 + threadIdx.x) >> 6;   // global wave id
    const int lane = threadIdx.x & 63;
    const int t    = lane >> 2;                               // anchor slot 0..15
    const int j    = lane & 3;                                // quarter 0..3
    const int a    = wid * 16 + t;                            // 25200 waves exact
    const float obj = objarr[a];                              // dense, broadcast x4
    unsigned cf = 0u;
    if (obj > 0.8f) {
        const float* cls = logits + (size_t)a * REC + 5 + j * 20;
        float v[20];
#pragma unroll
        for (int i = 0; i < 5; ++i) {
            float4 q = *(const float4*)(cls + 4 * i);
            v[4*i+0] = q.x; v[4*i+1] = q.y; v[4*i+2] = q.z; v[4*i+3] = q.w;
        }
        float m = v[0];
#pragma unroll
        for (int i = 1; i < 20; ++i) m = fmaxf(m, v[i]);
        m = fmaxf(m, __shfl_xor(m, 1));
        m = fmaxf(m, __shfl_xor(m, 2));
        int lc = 255;
#pragma unroll
        for (int i = 0; i < 20; ++i) lc = min(lc, (v[i] == m) ? (j * 20 + i) : 255);
        lc = min(lc, __shfl_xor(lc, 1));
        lc = min(lc, __shfl_xor(lc, 2));
        const float conf = obj * m;                           // exact: single multiply
        cf = (conf > 0.8f) ? __float_as_uint(conf) : 0u;
        if (j == 0) labout[a] = (unsigned)lc;
    }
    if (j == 0) confout[a] = cf;
}

// ---- kSel: select top-300 + sort + gather + pred outputs + targets ----
__global__ __launch_bounds__(1024) void kSel(const float* __restrict__ logits,
                                             const unsigned* __restrict__ confbits,
                                             const unsigned* __restrict__ labels,
                                             const float* __restrict__ targets,
                                             const int* __restrict__ tlen,
                                             float* __restrict__ out) {
    __shared__ unsigned hist[NBUCKET];
    __shared__ unsigned long long fin[FIN];
    __shared__ unsigned long long srt[MAXDET];
    __shared__ int sTb, sCnt;
    const int b = blockIdx.x;
    const int tid = threadIdx.x;
    const int lane = tid & 63;

    // ---- targets, folded into spare threads ----
    if (tid >= 512 && tid < 512 + TMAX) {
        int t = tid - 512;
        bool is64 = (tlen[1] == 0) && (tlen[3] == 0) && (tlen[5] == 0);
        int len = is64 ? tlen[2 * b] : tlen[b];
        const float* r = targets + ((size_t)b * TMAX + t) * 6;
        float cx = r[0], cy = r[1], w = r[2], h = r[3], sc = r[4], lb = r[5];
        float hw = opaque_f(w * 0.5f);
        float hh = opaque_f(h * 0.5f);
        size_t o = (size_t)b * TMAX + t;
        out[OFF_TB + o * 4 + 0] = cx - hw;
        out[OFF_TB + o * 4 + 1] = cy - hh;
        out[OFF_TB + o * 4 + 2] = cx + hw;
        out[OFF_TB + o * 4 + 3] = cy + hh;
        out[OFF_TS + o] = sc;
        out[OFF_TL + o] = (float)(int)lb;
        out[OFF_TV + o] = (t < len) ? 1.0f : 0.0f;
    }

    // ---- init ----
    for (int i = tid; i < NBUCKET; i += 1024) hist[i] = 0u;
    if (tid < MAXDET) srt[tid] = 0ull;
    if (tid == 0) sCnt = 0;
    __syncthreads();

    // ---- histogram ----
    const unsigned* cb = confbits + (size_t)b * NANCH;
    const uint4* cb4 = (const uint4*)cb;
#pragma unroll 1
    for (int i = tid; i < NANCH / 4; i += 1024) {
        uint4 u = cb4[i];
        unsigned w0 = u.x, w1 = u.y, w2 = u.z, w3 = u.w;
        if (w0) { unsigned bk = (w0 - 0x3F4CCCCDu) >> 11; if (bk > NBUCKET-1u) bk = NBUCKET-1u; atomicAdd(&hist[bk], 1u); }
        if (w1) { unsigned bk = (w1 - 0x3F4CCCCDu) >> 11; if (bk > NBUCKET-1u) bk = NBUCKET-1u; atomicAdd(&hist[bk], 1u); }
        if (w2) { unsigned bk = (w2 - 0x3F4CCCCDu) >> 11; if (bk > NBUCKET-1u) bk = NBUCKET-1u; atomicAdd(&hist[bk], 1u); }
        if (w3) { unsigned bk = (w3 - 0x3F4CCCCDu) >> 11; if (bk > NBUCKET-1u) bk = NBUCKET-1u; atomicAdd(&hist[bk], 1u); }
    }
    __syncthreads();

    // ---- threshold bucket tb, wave 0 ----
    if (tid < 64) {
        const int l = tid;
        unsigned sup = 0u;
        for (int j = 0; j < 32; ++j) sup += hist[l * 32 + j];
        unsigned ss = sup;
        for (int off = 1; off < 64; off <<= 1) {
            unsigned v = __shfl_down(ss, off);
            ss += (l + off < 64) ? v : 0u;
        }
        bool ge = ss >= MAXDET;
        unsigned long long mask = __ballot(ge);
        int sstar = (mask == 0ull) ? 0 : (63 - __clzll(mask));
        unsigned tail = (sstar < 63) ? __shfl(ss, sstar + 1) : 0u;
        unsigned h = (l < 32) ? hist[sstar * 32 + l] : 0u;
        unsigned s2 = h;
        for (int off = 1; off < 32; off <<= 1) {
            unsigned v = __shfl_down(s2, off);
            s2 += (l + off < 32) ? v : 0u;
        }
        bool ge2 = (l < 32) && (s2 + tail >= MAXDET);
        unsigned long long m2 = __ballot(ge2);
        int lstar = (m2 == 0ull) ? 0 : (63 - __clzll(m2));
        if (l == 0) sTb = sstar * 32 + lstar;
    }
    __syncthreads();

    // ---- compact >= threshold; wave-aggregated atomics ----
    const int tb = sTb;
#pragma unroll 1
    for (int i = tid; i < NANCH / 4; i += 1024) {
        uint4 u = cb4[i];
        unsigned wsv[4] = {u.x, u.y, u.z, u.w};
#pragma unroll
        for (int c = 0; c < 4; ++c) {
            unsigned bits = wsv[c];
            unsigned bk = (bits - 0x3F4CCCCDu) >> 11;
            if (bk > NBUCKET - 1u) bk = NBUCKET - 1u;
            bool pass = bits && ((int)bk >= tb);
            unsigned long long mk = __ballot(pass);
            if (mk) {
                int base = 0;
                if (lane == 0) base = atomicAdd(&sCnt, __popcll(mk));
                base = __shfl(base, 0);
                if (pass) {
                    int p = base + __popcll(mk & ((1ull << lane) - 1ull));
                    if (p < FIN)
                        fin[p] = ((unsigned long long)bits << 32) |
                                 (unsigned)(0xFFFFFFFFu - (unsigned)(i * 4 + c));
                }
            }
        }
    }
    __syncthreads();
    const int fc = (sCnt < FIN) ? sCnt : FIN;

    // ---- rank-scatter sort ----
    if (tid < fc) {
        unsigned long long k = fin[tid];
        int r = 0;
        for (int j = 0; j < fc; ++j) r += (fin[j] > k) ? 1 : 0;
        if (r < MAXDET) srt[r] = k;
    }
    __syncthreads();

    // ---- gather top-300: box float4 + precomputed label ----
    if (tid < MAXDET) {
        unsigned long long key = srt[tid];
        float score = __uint_as_float((unsigned)(key >> 32));
        unsigned n = 0xFFFFFFFFu - (unsigned)(key & 0xFFFFFFFFull);
        if (n >= NANCH) n = 0;
        const size_t ga = (size_t)b * NANCH + n;
        float4 bq = *(const float4*)(logits + ga * REC);
        unsigned lab = labels[ga];
        float hw = opaque_f(bq.z * 0.5f);  // block FMA contraction: match XLA rounding
        float hh = opaque_f(bq.w * 0.5f);
        float x1 = bq.x - hw, y1 = bq.y - hh, x2 = bq.x + hw, y2 = bq.y + hh;
        size_t o = (size_t)(b * MAXDET + tid);
        out[OFF_PB + o * 4 + 0] = x1;
        out[OFF_PB + o * 4 + 1] = y1;
        out[OFF_PB + o * 4 + 2] = x2;
        out[OFF_PB + o * 4 + 3] = y2;
        out[OFF_PS + o] = score;
        out[OFF_PL + o] = (float)lab;
    }
}

// ---- kSup: build suppression bitmatrix, 8 row-strip blocks per batch ----
// Reads boxes straight from out[OFF_PB] (float4-aligned). Ballot assembles
// 64 IoU decisions per wave-iter; lanes 0/32 plain-store words. No atomics.
__global__ __launch_bounds__(256) void kSup(const float* __restrict__ out,
                                            unsigned* __restrict__ suppg) {
    __shared__ float4 sb[MAXDET];
    __shared__ float sar[MAXDET];
    const int b = blockIdx.x >> 3;
    const int s = blockIdx.x & 7;
    const int tid = threadIdx.x;
    const int lane = tid & 63;
    const int w = tid >> 6;                       // wave 0..3
    const float4* boxes = (const float4*)(out + OFF_PB) + (size_t)b * MAXDET;
    for (int t = tid; t < MAXDET; t += 256) {
        float4 q = boxes[t];
        sb[t] = q;
        sar[t] = (q.z - q.x) * (q.w - q.y);       // same floats as (bx2-bx1)*(by2-by1)
    }
    __syncthreads();
    const int i0 = s * 38;
    const int i1 = min(i0 + 38, MAXDET);
    unsigned* sg = suppg + (size_t)b * SUPW;
    for (int i = i0 + w; i < i1; i += 4) {
        float4 bi = sb[i];                         // wave-uniform broadcast
        float ai = sar[i];
#pragma unroll
        for (int c = 0; c < 5; ++c) {
            int j = c * 64 + lane;
            bool pass = false;
            if (j < MAXDET && j > i) {
                float4 bj = sb[j];
                float aj = sar[j];
                float ltx = fmaxf(bi.x, bj.x);
                float lty = fmaxf(bi.y, bj.y);
                float rbx = fminf(bi.z, bj.z);
                float rby = fminf(bi.w, bj.w);
                float wx = fmaxf(rbx - ltx, 0.0f);
                float wy = fmaxf(rby - lty, 0.0f);
                float inter = wx * wy;
                float iou = inter / (ai + aj - inter + 1e-9f);  // left-to-right
                pass = (iou > 0.4f);
            }
            unsigned long long mk = __ballot(pass);
            if (lane == 0)  sg[i * 10 + 2 * c]     = (unsigned)mk;
            if (lane == 32) sg[i * 10 + 2 * c + 1] = (unsigned)(mk >> 32);
        }
    }
}

// ---- kScan: greedy NMS scan over the global bitmatrix ----
__global__ __launch_bounds__(512) void kScan(const unsigned* __restrict__ suppg,
                                             float* __restrict__ out) {
    __shared__ unsigned supp[MAXDET * 10];
    __shared__ unsigned keepw[10];
    const int b = blockIdx.x;
    const int tid = threadIdx.x;
    const unsigned* sg = suppg + (size_t)b * SUPW;
    for (int t = tid; t < MAXDET * 10; t += 512) supp[t] = sg[t];
    __syncthreads();
    if (tid < 64) {
        int q = tid;
        unsigned kw = (q < 10) ? ((q == 9) ? 0xFFFu : 0xFFFFFFFFu) : 0u;
        unsigned nextrow = (q < 10) ? supp[q] : 0u;
        for (int i = 0; i < MAXDET; ++i) {
            unsigned rowq = nextrow;
            if (q < 10 && i + 1 < MAXDET) nextrow = supp[(i + 1) * 10 + q];
            bool mybit = (q == (i >> 5)) && ((kw >> (i & 31)) & 1u);
            if (__ballot(mybit)) kw &= ~rowq;      // rows only contain j>i bits
        }
        if (q < 10) keepw[q] = kw;
    }
    __syncthreads();
    if (tid < MAXDET)
        out[OFF_PK + (size_t)b * MAXDET + tid] =
            ((keepw[tid >> 5] >> (tid & 31)) & 1u) ? 1.0f : 0.0f;
}

extern "C" void kernel_launch(void* const* d_in, const int* in_sizes, int n_in,
                              void* d_out, int out_size, void* d_ws, size_t ws_size,
                              hipStream_t stream) {
    const float* logits  = (const float*)d_in[0];
    const float* targets = (const float*)d_in[1];
    const int*   tlen    = (const int*)d_in[2];
    float* out = (float*)d_out;
    char* ws = (char*)d_ws;
    unsigned* confbits = (unsigned*)ws;                                 // 403200 u32
    unsigned* labels   = (unsigned*)(ws + (size_t)BATCH * NANCH * 4);   // 403200 u32
    float*    objarr   = (float*)   (ws + (size_t)BATCH * NANCH * 8);   // 403200 f32
    unsigned* suppg    = (unsigned*)(ws + (size_t)BATCH * NANCH * 12);  // 16*3008 u32

    hipLaunchKernelGGL(kA1, dim3(1575), dim3(256), 0, stream, logits, objarr);
    hipLaunchKernelGGL(kA2, dim3(6300), dim3(256), 0, stream,
                       logits, objarr, confbits, labels);
    hipLaunchKernelGGL(kSel, dim3(BATCH), dim3(1024), 0, stream,
                       logits, confbits, labels, targets, tlen, out);
    hipLaunchKernelGGL(kSup, dim3(BATCH * 8), dim3(256), 0, stream, out, suppg);
    hipLaunchKernelGGL(kScan, dim3(BATCH), dim3(512), 0, stream, suppg, out);
}

// Round 12
// 73.794 us; speedup vs baseline: 6.8363x; 1.0398x over previous
//
#include <hip/hip_runtime.h>
#include <stdint.h>

#define BATCH   16
#define NANCH   25200
#define NCLS    80
#define REC     85
#define MAXDET  300
#define TMAX    50
#define NBUCKET 2048
#define FIN     512

// output offsets (floats)
#define OFF_PB 0
#define OFF_PS 19200
#define OFF_PL 24000
#define OFF_PK 28800
#define OFF_TB 33600
#define OFF_TS 36800
#define OFF_TL 37600
#define OFF_TV 38400

__device__ __forceinline__ float opaque_f(float x) { asm volatile("" : "+v"(x)); return x; }

// ---- Kernel A: score+label, obj-gated (conf>0.8 requires obj>0.8 since
// cls_max<1). 4 lanes per anchor; obj read direct (one line per 4-group,
// broadcast). ~80% of anchors skip the 80-class read entirely. ----
__global__ __launch_bounds__(256) void kA(const float* __restrict__ logits,
                                          unsigned* __restrict__ confout,
                                          unsigned* __restrict__ labout) {
    const int wid  = (blockIdx.x * 256 + threadIdx.x) >> 6;   // global wave id
    const int lane = threadIdx.x & 63;
    const int t    = lane >> 2;                               // anchor slot 0..15
    const int j    = lane & 3;                                // quarter 0..3
    const int a    = wid * 16 + t;                            // 25200 waves exact
    const float obj = logits[(size_t)a * REC + 4];            // broadcast x4
    unsigned cf = 0u;
    if (obj > 0.8f) {
        const float* cls = logits + (size_t)a * REC + 5 + j * 20;
        float v[20];
#pragma unroll
        for (int i = 0; i < 5; ++i) {
            float4 q = *(const float4*)(cls + 4 * i);
            v[4*i+0] = q.x; v[4*i+1] = q.y; v[4*i+2] = q.z; v[4*i+3] = q.w;
        }
        float m = v[0];
#pragma unroll
        for (int i = 1; i < 20; ++i) m = fmaxf(m, v[i]);
        m = fmaxf(m, __shfl_xor(m, 1));                       // within 4-group
        m = fmaxf(m, __shfl_xor(m, 2));                       // all 4 lanes agree
        int lc = 255;                                         // first-match class
#pragma unroll
        for (int i = 0; i < 20; ++i) lc = min(lc, (v[i] == m) ? (j * 20 + i) : 255);
        lc = min(lc, __shfl_xor(lc, 1));
        lc = min(lc, __shfl_xor(lc, 2));                      // global first-max idx
        const float conf = obj * m;                           // exact: single multiply
        cf = (conf > 0.8f) ? __float_as_uint(conf) : 0u;
        if (j == 0) labout[a] = (unsigned)lc;
    }
    if (j == 0) confout[a] = cf;                              // every slot, every call
}

// ---- kFused: select top-300 + sort + gather + NMS (ballot build) + scan
//      + targets. One block per batch, 1024 threads. ----
__global__ __launch_bounds__(1024) void kFused(const float* __restrict__ logits,
                                               const unsigned* __restrict__ confbits,
                                               const unsigned* __restrict__ labels,
                                               const float* __restrict__ targets,
                                               const int* __restrict__ tlen,
                                               float* __restrict__ out) {
    __shared__ unsigned hist[NBUCKET];
    __shared__ unsigned long long fin[FIN];
    __shared__ unsigned long long srt[MAXDET];
    __shared__ float bx1[MAXDET], by1[MAXDET], bx2[MAXDET], by2[MAXDET];
    __shared__ float sar[MAXDET];
    __shared__ unsigned supp[MAXDET * 10];   // 300 rows x 320 bits
    __shared__ unsigned keepw[10];
    __shared__ int sTb, sCnt;
    const int b = blockIdx.x;
    const int tid = threadIdx.x;
    const int lane = tid & 63;
    const int w = tid >> 6;                  // wave 0..15

    // ---- targets, folded into spare threads ----
    if (tid >= 512 && tid < 512 + TMAX) {
        int t = tid - 512;
        bool is64 = (tlen[1] == 0) && (tlen[3] == 0) && (tlen[5] == 0);
        int len = is64 ? tlen[2 * b] : tlen[b];
        const float* r = targets + ((size_t)b * TMAX + t) * 6;
        float cx = r[0], cy = r[1], wd = r[2], h = r[3], sc = r[4], lb = r[5];
        float hw = opaque_f(wd * 0.5f);
        float hh = opaque_f(h * 0.5f);
        size_t o = (size_t)b * TMAX + t;
        out[OFF_TB + o * 4 + 0] = cx - hw;
        out[OFF_TB + o * 4 + 1] = cy - hh;
        out[OFF_TB + o * 4 + 2] = cx + hw;
        out[OFF_TB + o * 4 + 3] = cy + hh;
        out[OFF_TS + o] = sc;
        out[OFF_TL + o] = (float)(int)lb;
        out[OFF_TV + o] = (t < len) ? 1.0f : 0.0f;
    }

    // ---- init ----
    for (int i = tid; i < NBUCKET; i += 1024) hist[i] = 0u;
    if (tid < MAXDET) srt[tid] = 0ull;
    if (tid == 0) sCnt = 0;
    __syncthreads();

    // ---- histogram over this batch's conf bits (uint4) ----
    const unsigned* cb = confbits + (size_t)b * NANCH;
    const uint4* cb4 = (const uint4*)cb;
#pragma unroll 1
    for (int i = tid; i < NANCH / 4; i += 1024) {
        uint4 u = cb4[i];
        unsigned w0 = u.x, w1 = u.y, w2 = u.z, w3 = u.w;
        if (w0) { unsigned bk = (w0 - 0x3F4CCCCDu) >> 11; if (bk > NBUCKET-1u) bk = NBUCKET-1u; atomicAdd(&hist[bk], 1u); }
        if (w1) { unsigned bk = (w1 - 0x3F4CCCCDu) >> 11; if (bk > NBUCKET-1u) bk = NBUCKET-1u; atomicAdd(&hist[bk], 1u); }
        if (w2) { unsigned bk = (w2 - 0x3F4CCCCDu) >> 11; if (bk > NBUCKET-1u) bk = NBUCKET-1u; atomicAdd(&hist[bk], 1u); }
        if (w3) { unsigned bk = (w3 - 0x3F4CCCCDu) >> 11; if (bk > NBUCKET-1u) bk = NBUCKET-1u; atomicAdd(&hist[bk], 1u); }
    }
    __syncthreads();

    // ---- threshold bucket tb, wave 0 ----
    if (tid < 64) {
        const int l = tid;
        unsigned sup = 0u;
        for (int j = 0; j < 32; ++j) sup += hist[l * 32 + j];
        unsigned ss = sup;
        for (int off = 1; off < 64; off <<= 1) {
            unsigned v = __shfl_down(ss, off);
            ss += (l + off < 64) ? v : 0u;
        }
        bool ge = ss >= MAXDET;
        unsigned long long mask = __ballot(ge);
        int sstar = (mask == 0ull) ? 0 : (63 - __clzll(mask));
        unsigned tail = (sstar < 63) ? __shfl(ss, sstar + 1) : 0u;
        unsigned h = (l < 32) ? hist[sstar * 32 + l] : 0u;
        unsigned s2 = h;
        for (int off = 1; off < 32; off <<= 1) {
            unsigned v = __shfl_down(s2, off);
            s2 += (l + off < 32) ? v : 0u;
        }
        bool ge2 = (l < 32) && (s2 + tail >= MAXDET);
        unsigned long long m2 = __ballot(ge2);
        int lstar = (m2 == 0ull) ? 0 : (63 - __clzll(m2));
        if (l == 0) sTb = sstar * 32 + lstar;
    }
    __syncthreads();

    // ---- compact >= threshold; wave-aggregated atomics ----
    const int tb = sTb;
#pragma unroll 1
    for (int i = tid; i < NANCH / 4; i += 1024) {
        uint4 u = cb4[i];
        unsigned wsv[4] = {u.x, u.y, u.z, u.w};
#pragma unroll
        for (int c = 0; c < 4; ++c) {
            unsigned bits = wsv[c];
            unsigned bk = (bits - 0x3F4CCCCDu) >> 11;
            if (bk > NBUCKET - 1u) bk = NBUCKET - 1u;
            bool pass = bits && ((int)bk >= tb);
            unsigned long long mk = __ballot(pass);
            if (mk) {
                int base = 0;
                if (lane == 0) base = atomicAdd(&sCnt, __popcll(mk));
                base = __shfl(base, 0);
                if (pass) {
                    int p = base + __popcll(mk & ((1ull << lane) - 1ull));
                    if (p < FIN)
                        fin[p] = ((unsigned long long)bits << 32) |
                                 (unsigned)(0xFFFFFFFFu - (unsigned)(i * 4 + c));
                }
            }
        }
    }
    __syncthreads();
    const int fc = (sCnt < FIN) ? sCnt : FIN;

    // ---- rank-scatter sort: rank = #{keys > mine}; keys unique ----
    if (tid < fc) {
        unsigned long long k = fin[tid];
        int r = 0;
        for (int j = 0; j < fc; ++j) r += (fin[j] > k) ? 1 : 0;
        if (r < MAXDET) srt[r] = k;
    }
    __syncthreads();

    // ---- gather top-300: box float4 + precomputed label ----
    if (tid < MAXDET) {
        unsigned long long key = srt[tid];
        float score = __uint_as_float((unsigned)(key >> 32));
        unsigned n = 0xFFFFFFFFu - (unsigned)(key & 0xFFFFFFFFull);
        if (n >= NANCH) n = 0;
        const size_t ga = (size_t)b * NANCH + n;
        float4 bq = *(const float4*)(logits + ga * REC);
        unsigned lab = labels[ga];
        float hw = opaque_f(bq.z * 0.5f);  // block FMA contraction: match XLA rounding
        float hh = opaque_f(bq.w * 0.5f);
        float x1 = bq.x - hw, y1 = bq.y - hh, x2 = bq.x + hw, y2 = bq.y + hh;
        bx1[tid] = x1; by1[tid] = y1; bx2[tid] = x2; by2[tid] = y2;
        sar[tid] = (x2 - x1) * (y2 - y1);      // same floats as reference area
        size_t o = (size_t)(b * MAXDET + tid);
        out[OFF_PB + o * 4 + 0] = x1;
        out[OFF_PB + o * 4 + 1] = y1;
        out[OFF_PB + o * 4 + 2] = x2;
        out[OFF_PB + o * 4 + 3] = y2;
        out[OFF_PS + o] = score;
        out[OFF_PL + o] = (float)lab;
    }
    __syncthreads();

    // ---- suppression matrix: ballot build, all 16 waves, no atomics ----
    for (int i = w; i < MAXDET; i += 16) {
        float p1 = bx1[i], q1 = by1[i], p2 = bx2[i], q2 = by2[i];  // wave-uniform
        float ai = sar[i];
#pragma unroll
        for (int c = 0; c < 5; ++c) {
            int j = c * 64 + lane;
            bool pass = false;
            if (j < MAXDET && j > i) {
                float ltx = fmaxf(p1, bx1[j]);
                float lty = fmaxf(q1, by1[j]);
                float rbx = fminf(p2, bx2[j]);
                float rby = fminf(q2, by2[j]);
                float wx = fmaxf(rbx - ltx, 0.0f);
                float wy = fmaxf(rby - lty, 0.0f);
                float inter = wx * wy;
                float iou = inter / (ai + sar[j] - inter + 1e-9f);  // left-to-right
                pass = (iou > 0.4f);
            }
            unsigned long long mk = __ballot(pass);
            if (lane == 0)  supp[i * 10 + 2 * c]     = (unsigned)mk;
            if (lane == 32) supp[i * 10 + 2 * c + 1] = (unsigned)(mk >> 32);
        }
    }
    __syncthreads();

    // ---- greedy scan: wave 0, lane q owns keep word q ----
    if (tid < 64) {
        int q = tid;
        unsigned kw = (q < 10) ? ((q == 9) ? 0xFFFu : 0xFFFFFFFFu) : 0u;
        unsigned nextrow = (q < 10) ? supp[q] : 0u;
        for (int i = 0; i < MAXDET; ++i) {
            unsigned rowq = nextrow;
            if (q < 10 && i + 1 < MAXDET) nextrow = supp[(i + 1) * 10 + q];
            bool mybit = (q == (i >> 5)) && ((kw >> (i & 31)) & 1u);
            if (__ballot(mybit)) kw &= ~rowq;      // rows only contain j>i bits
        }
        if (q < 10) keepw[q] = kw;
    }
    __syncthreads();
    if (tid < MAXDET)
        out[OFF_PK + (size_t)b * MAXDET + tid] =
            ((keepw[tid >> 5] >> (tid & 31)) & 1u) ? 1.0f : 0.0f;
}

extern "C" void kernel_launch(void* const* d_in, const int* in_sizes, int n_in,
                              void* d_out, int out_size, void* d_ws, size_t ws_size,
                              hipStream_t stream) {
    const float* logits  = (const float*)d_in[0];
    const float* targets = (const float*)d_in[1];
    const int*   tlen    = (const int*)d_in[2];
    float* out = (float*)d_out;
    char* ws = (char*)d_ws;
    unsigned* confbits = (unsigned*)ws;                                 // 403200 u32
    unsigned* labels   = (unsigned*)(ws + (size_t)BATCH * NANCH * 4);   // 403200 u32

    // 403200 anchors / 16 per wave = 25200 waves / 4 per block = 6300 blocks
    hipLaunchKernelGGL(kA, dim3(6300), dim3(256), 0, stream, logits, confbits, labels);
    hipLaunchKernelGGL(kFused, dim3(BATCH), dim3(1024), 0, stream,
                       logits, confbits, labels, targets, tlen, out);
}